// Round 1
// 798.931 us; speedup vs baseline: 1.0512x; 1.0512x over previous
//
#include <hip/hip_runtime.h>

#define Nn 50000
#define Ee 600000
#define Hd 128
#define Ld 4
#define Kd 3

typedef __attribute__((ext_vector_type(8))) short short8;
typedef __attribute__((ext_vector_type(4))) float float4v;

union U4 { uint4 u; short8 s; };

__device__ __forceinline__ unsigned bf16rne(float f) {
    unsigned u = __float_as_uint(f);
    return (u + 0x7fffu + ((u >> 16) & 1u)) >> 16;
}
__device__ __forceinline__ float bf16lo(unsigned v) { return __uint_as_float(v << 16); }
__device__ __forceinline__ float bf16hi(unsigned v) { return __uint_as_float(v & 0xffff0000u); }

__global__ void zero_int_kernel(int* __restrict__ p, int n) {
    int i = blockIdx.x * blockDim.x + threadIdx.x;
    int stride = gridDim.x * blockDim.x;
    for (; i < n; i += stride) p[i] = 0;
}

__global__ void count_kernel(const int* __restrict__ col, int* __restrict__ deg) {
    int e = blockIdx.x * blockDim.x + threadIdx.x;
    if (e < Ee) atomicAdd(&deg[col[e]], 1);
}

// Shfl-based exclusive scan.
__global__ void scan_kernel(const int* __restrict__ deg, int* __restrict__ starts,
                            float* __restrict__ dinv) {
    __shared__ int wsum[16];
    __shared__ int carry_s;
    int tid = threadIdx.x;
    int lane = tid & 63, w = tid >> 6;
    if (tid == 0) carry_s = 0;
    __syncthreads();
    for (int base = 0; base < Nn; base += 1024) {
        int i = base + tid;
        int v = (i < Nn) ? deg[i] : 0;
        if (i < Nn) dinv[i] = (v > 0) ? rsqrtf((float)v) : 0.0f;
        int s = v;
#pragma unroll
        for (int off = 1; off < 64; off <<= 1) {
            int t = __shfl_up(s, off);
            if (lane >= off) s += t;
        }
        if (lane == 63) wsum[w] = s;
        __syncthreads();
        if (w == 0) {
            int ws = (lane < 16) ? wsum[lane] : 0;
#pragma unroll
            for (int off = 1; off < 16; off <<= 1) {
                int t = __shfl_up(ws, off);
                if (lane >= off) ws += t;
            }
            if (lane < 16) wsum[lane] = ws;
        }
        __syncthreads();
        int woff = (w > 0) ? wsum[w - 1] : 0;
        int carry = carry_s;
        if (i < Nn) starts[i] = carry + woff + s - v;
        __syncthreads();
        if (tid == 1023) carry_s = carry + wsum[15];
    }
    __syncthreads();
    if (threadIdx.x == 0) starts[Nn] = carry_s;
}

// CSR fill; writes ea_s (slot-ordered edge attrs) directly.
__global__ void fill_kernel(const int* __restrict__ row, const int* __restrict__ col,
                            const int* __restrict__ starts, int* __restrict__ cnt,
                            const float* __restrict__ dinv, const float* __restrict__ ea,
                            int* __restrict__ src_s, float* __restrict__ w_s,
                            float4* __restrict__ ea_s) {
    int e = blockIdx.x * blockDim.x + threadIdx.x;
    if (e < Ee) {
        int c = col[e], r = row[e];
        float4 ev = *(const float4*)&ea[(size_t)e * 4];
        int slot = starts[c] + atomicAdd(&cnt[c], 1);
        src_s[slot] = r;
        w_s[slot] = dinv[r] * dinv[c];
        ea_s[slot] = ev;
    }
}

// x [N][7] -> padded aligned xp [N][8] (pad = 0)
__global__ void xpack_kernel(const float* __restrict__ x, float* __restrict__ xp) {
    int i = blockIdx.x * blockDim.x + threadIdx.x;
    if (i < Nn) {
        float4 a = make_float4(x[i * 7], x[i * 7 + 1], x[i * 7 + 2], x[i * 7 + 3]);
        float4 b = make_float4(x[i * 7 + 4], x[i * 7 + 5], x[i * 7 + 6], 0.0f);
        *(float4*)&xp[i * 8] = a;
        *(float4*)&xp[i * 8 + 4] = b;
    }
}

// Decoupled gather: xjs[slot] = xp[src_s[slot]] (32 B rows, slot-ordered out).
__global__ void xgather_kernel(const int* __restrict__ src_s, const float* __restrict__ xp,
                               float* __restrict__ xjs) {
    int gid = blockIdx.x * blockDim.x + threadIdx.x;
    int slot = gid >> 1, part = gid & 1;
    if (slot < Ee) {
        int src = src_s[slot];
        float4 v = *(const float4*)&xp[(size_t)src * 8 + part * 4];
        *(float4*)&xjs[(size_t)slot * 8 + part * 4] = v;
    }
}

// 17 weight matrices [k][n] fp32 -> FRAGMENT-SWIZZLED bf16 hi/lo planes.
__global__ void wconv_kernel(const float* __restrict__ eW2, const float* __restrict__ tagW,
                             unsigned short* __restrict__ WThi,
                             unsigned short* __restrict__ WTlo) {
    int id = blockIdx.x * blockDim.x + threadIdx.x;
    if (id >= 17 * 16384) return;
    int m = id >> 14;
    int rem = id & 16383;
    int n = rem >> 7, k = rem & 127;
    const float* src = (m == 0) ? eW2 : tagW + (size_t)(m - 1) * 16384;
    float f = src[k * Hd + n];
    unsigned h = bf16rne(f);
    float r = f - __uint_as_float(h << 16);
    int kc = k >> 5, quad = (k >> 3) & 3, j = k & 7;
    int nt = n >> 4, l15 = n & 15;
    int lane = quad * 16 + l15;
    int idx = (m << 14) + (((kc * 8 + nt) * 64) + lane) * 8 + j;
    WThi[idx] = (unsigned short)h;
    WTlo[idx] = (unsigned short)bf16rne(r);
}

// Layer-1-only edge pass v4: wave-uniform node/slot forced into SGPRs via
// readfirstlane so xp/xjs/ea_s loads become scalar (s_load) and address math
// goes SALU; FMAs read one SGPR operand. Math order identical to v3.
__global__ __launch_bounds__(256) void edge_l1_kernel(
    const float* __restrict__ xp, const float* __restrict__ xjs,
    const float4* __restrict__ ea_s,
    const int* __restrict__ starts,
    const float* __restrict__ eW1, const float* __restrict__ eb1,
    unsigned short* __restrict__ tout) {
    int lane = threadIdx.x & 63;
    float w1x[18], w1y[18];
#pragma unroll
    for (int j = 0; j < 18; ++j) {
        w1x[j] = eW1[j * Hd + lane];
        w1y[j] = eW1[j * Hd + lane + 64];
    }
    float b1x = eb1[lane], b1y = eb1[lane + 64];
    int wid = __builtin_amdgcn_readfirstlane(
        (int)((blockIdx.x * 256u + threadIdx.x) >> 6));
    int nw = (gridDim.x * 256) >> 6;
    for (int node = wid; node < Nn; node += nw) {
        int s0 = starts[node], s1 = starts[node + 1];
        float4 p0 = *(const float4*)&xp[node * 8];
        float4 p1 = *(const float4*)&xp[node * 8 + 4];
        float prex = b1x + p0.x * w1x[0] + p0.y * w1x[1] + p0.z * w1x[2] + p0.w * w1x[3]
                   + p1.x * w1x[4] + p1.y * w1x[5] + p1.z * w1x[6];
        float prey = b1y + p0.x * w1y[0] + p0.y * w1y[1] + p0.z * w1y[2] + p0.w * w1y[3]
                   + p1.x * w1y[4] + p1.y * w1y[5] + p1.z * w1y[6];
        float accx = 0.0f, accy = 0.0f;
        int slot = s0;
        for (; slot + 2 <= s1; slot += 2) {
            float4 a0 = *(const float4*)&xjs[(size_t)slot * 8];
            float4 a1 = *(const float4*)&xjs[(size_t)slot * 8 + 4];
            float4 b0 = *(const float4*)&xjs[(size_t)(slot + 1) * 8];
            float4 b1v = *(const float4*)&xjs[(size_t)(slot + 1) * 8 + 4];
            float4 eA = ea_s[slot], eB = ea_s[slot + 1];
            float u0 = prex + a0.x * w1x[7] + a0.y * w1x[8] + a0.z * w1x[9] + a0.w * w1x[10]
                     + a1.x * w1x[11] + a1.y * w1x[12] + a1.z * w1x[13]
                     + eA.x * w1x[14] + eA.y * w1x[15] + eA.z * w1x[16] + eA.w * w1x[17];
            float u1 = prey + a0.x * w1y[7] + a0.y * w1y[8] + a0.z * w1y[9] + a0.w * w1y[10]
                     + a1.x * w1y[11] + a1.y * w1y[12] + a1.z * w1y[13]
                     + eA.x * w1y[14] + eA.y * w1y[15] + eA.z * w1y[16] + eA.w * w1y[17];
            float v0 = prex + b0.x * w1x[7] + b0.y * w1x[8] + b0.z * w1x[9] + b0.w * w1x[10]
                     + b1v.x * w1x[11] + b1v.y * w1x[12] + b1v.z * w1x[13]
                     + eB.x * w1x[14] + eB.y * w1x[15] + eB.z * w1x[16] + eB.w * w1x[17];
            float v1 = prey + b0.x * w1y[7] + b0.y * w1y[8] + b0.z * w1y[9] + b0.w * w1y[10]
                     + b1v.x * w1y[11] + b1v.y * w1y[12] + b1v.z * w1y[13]
                     + eB.x * w1y[14] + eB.y * w1y[15] + eB.z * w1y[16] + eB.w * w1y[17];
            accx += fmaxf(u0, 0.0f) + fmaxf(v0, 0.0f);
            accy += fmaxf(u1, 0.0f) + fmaxf(v1, 0.0f);
        }
        if (slot < s1) {
            float4 a0 = *(const float4*)&xjs[(size_t)slot * 8];
            float4 a1 = *(const float4*)&xjs[(size_t)slot * 8 + 4];
            float4 eA = ea_s[slot];
            float u0 = prex + a0.x * w1x[7] + a0.y * w1x[8] + a0.z * w1x[9] + a0.w * w1x[10]
                     + a1.x * w1x[11] + a1.y * w1x[12] + a1.z * w1x[13]
                     + eA.x * w1x[14] + eA.y * w1x[15] + eA.z * w1x[16] + eA.w * w1x[17];
            float u1 = prey + a0.x * w1y[7] + a0.y * w1y[8] + a0.z * w1y[9] + a0.w * w1y[10]
                     + a1.x * w1y[11] + a1.y * w1y[12] + a1.z * w1y[13]
                     + eA.x * w1y[14] + eA.y * w1y[15] + eA.z * w1y[16] + eA.w * w1y[17];
            accx += fmaxf(u0, 0.0f);
            accy += fmaxf(u1, 0.0f);
        }
        tout[node * Hd + lane] = (unsigned short)bf16rne(accx);
        tout[node * Hd + lane + 64] = (unsigned short)bf16rne(accy);
    }
}

// MFMA multi-source GEMM, all-bf16 A path (2 mfma/k-step uniform), LDS-free
// K-loop, fragment-swizzled W. Output is bf16 only (Cb16); when yout is
// non-null (final layer) the head y = C @ oW + ob is fused and Cb16 skipped.
__global__ __launch_bounds__(256, 2) void tag_gemm_mfma(
    const unsigned short* __restrict__ P0,
    const unsigned short* __restrict__ Pb1, const unsigned short* __restrict__ Pb2,
    const unsigned short* __restrict__ Pb3,
    const unsigned short* __restrict__ WThi, const unsigned short* __restrict__ WTlo,
    const float* __restrict__ bias, const int* __restrict__ rowdeg,
    unsigned short* __restrict__ Cb16,
    const float* __restrict__ oW, const float* __restrict__ ob,
    float* __restrict__ yout, int nsrc, int reluflag) {
    __shared__ float Cl[64 * 133];
    __shared__ float oWs[256];
    __shared__ float obs[2];
    const int tid = threadIdx.x;
    const int lane = tid & 63;
    const int wv = tid >> 6;
    const int l15 = lane & 15;
    const int quad = lane >> 4;
    const int rowbase = blockIdx.x * 64;
    const int arow = min(rowbase + wv * 16 + l15, Nn - 1);
    if (yout) {
        oWs[tid] = oW[tid & 255];
        if (tid < 2) obs[tid] = ob[tid];
    }

    float4v acc[8];
#pragma unroll
    for (int nt = 0; nt < 8; ++nt) acc[nt] = (float4v)0.0f;

#pragma unroll 1
    for (int g = 0; g < nsrc; ++g) {
        const unsigned short* Pb = (g == 0) ? P0 : (g == 1) ? Pb1 : (g == 2) ? Pb2 : Pb3;
        const unsigned short* Whg = WThi + (size_t)g * 16384;
        const unsigned short* Wlg = WTlo + (size_t)g * 16384;
#pragma unroll
        for (int kc = 0; kc < 4; ++kc) {
            U4 ab;
            ab.u = *(const uint4*)&Pb[(size_t)arow * Hd + kc * 32 + quad * 8];
            const unsigned short* whp = Whg + (size_t)(kc * 8) * 512 + lane * 8;
            const unsigned short* wlp = Wlg + (size_t)(kc * 8) * 512 + lane * 8;
#pragma unroll
            for (int nt = 0; nt < 8; ++nt) {
                U4 wh, wl;
                wh.u = *(const uint4*)&whp[nt * 512];
                wl.u = *(const uint4*)&wlp[nt * 512];
                acc[nt] = __builtin_amdgcn_mfma_f32_16x16x32_bf16(ab.s, wh.s, acc[nt], 0, 0, 0);
                acc[nt] = __builtin_amdgcn_mfma_f32_16x16x32_bf16(ab.s, wl.s, acc[nt], 0, 0, 0);
            }
        }
    }
#pragma unroll
    for (int nt = 0; nt < 8; ++nt)
#pragma unroll
        for (int reg = 0; reg < 4; ++reg)
            Cl[(wv * 16 + quad * 4 + reg) * 133 + nt * 16 + l15] = acc[nt][reg];
    __syncthreads();
#pragma unroll
    for (int i = 0; i < 8; ++i) {
        int s = tid + i * 256;
        int r = s >> 5, c4 = (s & 31) * 4;
        int grow = rowbase + r;
        if (grow < Nn) {
            float4 v = *(const float4*)&Cl[r * 133 + c4];
            float4 bv = *(const float4*)&bias[c4];
            float bs = rowdeg ? (float)rowdeg[grow] : 1.0f;
            v.x += bs * bv.x; v.y += bs * bv.y; v.z += bs * bv.z; v.w += bs * bv.w;
            if (reluflag) {
                v.x = fmaxf(v.x, 0.0f); v.y = fmaxf(v.y, 0.0f);
                v.z = fmaxf(v.z, 0.0f); v.w = fmaxf(v.w, 0.0f);
            }
            if (yout) {
                *(float4*)&Cl[r * 133 + c4] = v;  // keep for the fused head
            } else {
                uint2 p;
                p.x = bf16rne(v.x) | (bf16rne(v.y) << 16);
                p.y = bf16rne(v.z) | (bf16rne(v.w) << 16);
                *(uint2*)&Cb16[(size_t)grow * Hd + c4] = p;
            }
        }
    }
    if (yout) {
        __syncthreads();
        if (tid < 64) {
            int grow = rowbase + tid;
            if (grow < Nn) {
                float a0 = obs[0], a1 = obs[1];
#pragma unroll
                for (int c = 0; c < Hd; c += 4) {
                    float4 t = *(const float4*)&Cl[tid * 133 + c];
                    a0 += t.x * oWs[2 * c] + t.y * oWs[2 * c + 2]
                        + t.z * oWs[2 * c + 4] + t.w * oWs[2 * c + 6];
                    a1 += t.x * oWs[2 * c + 1] + t.y * oWs[2 * c + 3]
                        + t.z * oWs[2 * c + 5] + t.w * oWs[2 * c + 7];
                }
                *(float2*)&yout[(size_t)grow * 2] = make_float2(a0, a1);
            }
        }
    }
}

// bf16 hop v6: full-wave per slot (lane owns features 2l,2l+1), scalar
// src/w via uniform node (readfirstlane), 4 independent gather streams with
// software-pipelined scalar prefetch of the next slot-group, clamped tail
// (zero weight) so there is no serialized remainder. Summation order matches
// v5's quarter-split + shfl tree exactly (stream j = slots s0+j, s0+j+4, ...;
// merge (s0+s1)+(s2+s3)).
__global__ __launch_bounds__(256) void hop_kernel(
    const unsigned short* __restrict__ pin, unsigned short* __restrict__ pout,
    const int* __restrict__ starts, const int* __restrict__ src_s,
    const float* __restrict__ w_s) {
    int lane = threadIdx.x & 63;
    int node = __builtin_amdgcn_readfirstlane(
        (int)((blockIdx.x * 256u + threadIdx.x) >> 6));
    if (node >= Nn) return;
    int s0 = starts[node], s1 = starts[node + 1];
    const unsigned* pin32 = (const unsigned*)pin;
    unsigned* pout32 = (unsigned*)pout;
    float a0 = 0.0f, a1 = 0.0f, b0 = 0.0f, b1 = 0.0f;
    float c0 = 0.0f, c1 = 0.0f, d0 = 0.0f, d1 = 0.0f;
    if (s1 > s0) {
        int sl = s1 - 1;
        int p1i = min(s0 + 1, sl), p2i = min(s0 + 2, sl), p3i = min(s0 + 3, sl);
        int r0 = src_s[s0], r1 = src_s[p1i], r2 = src_s[p2i], r3 = src_s[p3i];
        float w0 = w_s[s0];
        float w1 = (s0 + 1 < s1) ? w_s[p1i] : 0.0f;
        float w2 = (s0 + 2 < s1) ? w_s[p2i] : 0.0f;
        float w3 = (s0 + 3 < s1) ? w_s[p3i] : 0.0f;
        for (int base = s0 + 4;; base += 4) {
            unsigned v0 = pin32[(size_t)r0 * 64 + lane];
            unsigned v1 = pin32[(size_t)r1 * 64 + lane];
            unsigned v2 = pin32[(size_t)r2 * 64 + lane];
            unsigned v3 = pin32[(size_t)r3 * 64 + lane];
            bool more = base < s1;
            int nr0 = r0, nr1 = r1, nr2 = r2, nr3 = r3;
            float x0 = 0.0f, x1 = 0.0f, x2 = 0.0f, x3 = 0.0f;
            if (more) {
                int q1 = min(base + 1, sl), q2 = min(base + 2, sl), q3 = min(base + 3, sl);
                nr0 = src_s[base]; nr1 = src_s[q1]; nr2 = src_s[q2]; nr3 = src_s[q3];
                x0 = w_s[base];
                x1 = (base + 1 < s1) ? w_s[q1] : 0.0f;
                x2 = (base + 2 < s1) ? w_s[q2] : 0.0f;
                x3 = (base + 3 < s1) ? w_s[q3] : 0.0f;
            }
            a0 += w0 * bf16lo(v0); a1 += w0 * bf16hi(v0);
            b0 += w1 * bf16lo(v1); b1 += w1 * bf16hi(v1);
            c0 += w2 * bf16lo(v2); c1 += w2 * bf16hi(v2);
            d0 += w3 * bf16lo(v3); d1 += w3 * bf16hi(v3);
            if (!more) break;
            r0 = nr0; r1 = nr1; r2 = nr2; r3 = nr3;
            w0 = x0; w1 = x1; w2 = x2; w3 = x3;
        }
    }
    float m0 = (a0 + b0) + (c0 + d0);
    float m1 = (a1 + b1) + (c1 + d1);
    unsigned o = bf16rne(m0) | (bf16rne(m1) << 16);
    pout32[(size_t)node * 64 + lane] = o;
}

extern "C" void kernel_launch(void* const* d_in, const int* in_sizes, int n_in,
                              void* d_out, int out_size, void* d_ws, size_t ws_size,
                              hipStream_t stream) {
    const float* x    = (const float*)d_in[0];
    const int*   ei   = (const int*)d_in[1];
    const float* ea   = (const float*)d_in[2];
    const float* eW1  = (const float*)d_in[3];
    const float* eb1  = (const float*)d_in[4];
    const float* eW2  = (const float*)d_in[5];
    const float* eb2  = (const float*)d_in[6];
    const float* tagW = (const float*)d_in[7];
    const float* tagb = (const float*)d_in[8];
    const float* oW   = (const float*)d_in[9];
    const float* ob   = (const float*)d_in[10];
    float* y = (float*)d_out;
    const int* row = ei;        // source
    const int* col = ei + Ee;   // target

    char* wp = (char*)d_ws;
    auto carve = [&](size_t bytes) -> char* {
        char* p = wp;
        wp += (bytes + 15) & ~(size_t)15;
        return p;
    };
    int* deg     = (int*)carve((size_t)2 * Nn * 4);
    int* cnt     = deg + Nn;
    int* starts  = (int*)carve((size_t)(Nn + 1) * 4);
    float* dinv  = (float*)carve((size_t)Nn * 4);
    int* src_s   = (int*)carve((size_t)Ee * 4);
    float* w_s   = (float*)carve((size_t)Ee * 4);
    float4* ea_s = (float4*)carve((size_t)Ee * 16);
    unsigned short* WThi = (unsigned short*)carve((size_t)17 * 16384 * 2);
    unsigned short* WTlo = (unsigned short*)carve((size_t)17 * 16384 * 2);
    unsigned short* t16  = (unsigned short*)carve((size_t)Nn * Hd * 2);
    unsigned short* h16a = (unsigned short*)carve((size_t)Nn * Hd * 2);
    unsigned short* h16b = (unsigned short*)carve((size_t)Nn * Hd * 2);
    unsigned short* pb0  = (unsigned short*)carve((size_t)Nn * Hd * 2);
    unsigned short* pb1  = (unsigned short*)carve((size_t)Nn * Hd * 2);
    unsigned short* pb2  = (unsigned short*)carve((size_t)Nn * Hd * 2);
    // aliases (dead before their regions are first written):
    float* xp  = (float*)pb2;   // 1.6 MB; pb2 first written at hop k=3
    float* xjs = (float*)h16b;  // 19.2 MB spans h16b+pb0; first written layer-0 gemm/hop

    zero_int_kernel<<<400, 256, 0, stream>>>(deg, 2 * Nn);
    count_kernel<<<(Ee + 255) / 256, 256, 0, stream>>>(col, deg);
    wconv_kernel<<<(17 * 16384 + 255) / 256, 256, 0, stream>>>(eW2, tagW, WThi, WTlo);
    xpack_kernel<<<(Nn + 255) / 256, 256, 0, stream>>>(x, xp);
    scan_kernel<<<1, 1024, 0, stream>>>(deg, starts, dinv);
    fill_kernel<<<(Ee + 255) / 256, 256, 0, stream>>>(row, col, starts, cnt, dinv, ea,
                                                      src_s, w_s, ea_s);
    xgather_kernel<<<(2 * Ee + 255) / 256, 256, 0, stream>>>(src_s, xp, xjs);
    // t = per-target sum of relu(layer1), bf16 (into t16)
    edge_l1_kernel<<<6250, 256, 0, stream>>>(xp, xjs, ea_s, starts, eW1, eb1, t16);
    // h0 = t @ W2 + deg*b2  (bf16 into h16a)
    const int gemm_grid = (Nn + 63) / 64;
    tag_gemm_mfma<<<gemm_grid, 256, 0, stream>>>(t16, nullptr, nullptr, nullptr,
                                                 WThi, WTlo, eb2, deg, h16a,
                                                 nullptr, nullptr, nullptr, 1, 0);

    unsigned short* hin = h16a;
    unsigned short* hout = h16b;
    for (int l = 0; l < Ld; ++l) {
        hop_kernel<<<12500, 256, 0, stream>>>(hin, pb0, starts, src_s, w_s);
        hop_kernel<<<12500, 256, 0, stream>>>(pb0, pb1, starts, src_s, w_s);
        hop_kernel<<<12500, 256, 0, stream>>>(pb1, pb2, starts, src_s, w_s);
        int last = (l == Ld - 1);
        tag_gemm_mfma<<<gemm_grid, 256, 0, stream>>>(
            hin, pb0, pb1, pb2,
            WThi + (size_t)(1 + l * 4) * 16384, WTlo + (size_t)(1 + l * 4) * 16384,
            tagb + l * Hd, nullptr, last ? nullptr : hout,
            last ? oW : nullptr, last ? ob : nullptr, last ? y : nullptr,
            4, last ? 0 : 1);
        unsigned short* t = hin; hin = hout; hout = t;
    }
}

// Round 2
// 772.158 us; speedup vs baseline: 1.0876x; 1.0347x over previous
//
#include <hip/hip_runtime.h>

#define Nn 50000
#define Ee 600000
#define Hd 128
#define Ld 4
#define Kd 3

typedef __attribute__((ext_vector_type(8))) short short8;
typedef __attribute__((ext_vector_type(4))) float float4v;

union U4 { uint4 u; short8 s; };

__device__ __forceinline__ unsigned bf16rne(float f) {
    unsigned u = __float_as_uint(f);
    return (u + 0x7fffu + ((u >> 16) & 1u)) >> 16;
}
__device__ __forceinline__ float bf16lo(unsigned v) { return __uint_as_float(v << 16); }
__device__ __forceinline__ float bf16hi(unsigned v) { return __uint_as_float(v & 0xffff0000u); }

__global__ void zero_int_kernel(int* __restrict__ p, int n) {
    int i = blockIdx.x * blockDim.x + threadIdx.x;
    int stride = gridDim.x * blockDim.x;
    for (; i < n; i += stride) p[i] = 0;
}

__global__ void count_kernel(const int* __restrict__ col, int* __restrict__ deg) {
    int e = blockIdx.x * blockDim.x + threadIdx.x;
    if (e < Ee) atomicAdd(&deg[col[e]], 1);
}

// Shfl-based exclusive scan.
__global__ void scan_kernel(const int* __restrict__ deg, int* __restrict__ starts,
                            float* __restrict__ dinv) {
    __shared__ int wsum[16];
    __shared__ int carry_s;
    int tid = threadIdx.x;
    int lane = tid & 63, w = tid >> 6;
    if (tid == 0) carry_s = 0;
    __syncthreads();
    for (int base = 0; base < Nn; base += 1024) {
        int i = base + tid;
        int v = (i < Nn) ? deg[i] : 0;
        if (i < Nn) dinv[i] = (v > 0) ? rsqrtf((float)v) : 0.0f;
        int s = v;
#pragma unroll
        for (int off = 1; off < 64; off <<= 1) {
            int t = __shfl_up(s, off);
            if (lane >= off) s += t;
        }
        if (lane == 63) wsum[w] = s;
        __syncthreads();
        if (w == 0) {
            int ws = (lane < 16) ? wsum[lane] : 0;
#pragma unroll
            for (int off = 1; off < 16; off <<= 1) {
                int t = __shfl_up(ws, off);
                if (lane >= off) ws += t;
            }
            if (lane < 16) wsum[lane] = ws;
        }
        __syncthreads();
        int woff = (w > 0) ? wsum[w - 1] : 0;
        int carry = carry_s;
        if (i < Nn) starts[i] = carry + woff + s - v;
        __syncthreads();
        if (tid == 1023) carry_s = carry + wsum[15];
    }
    __syncthreads();
    if (threadIdx.x == 0) starts[Nn] = carry_s;
}

// CSR fill; writes ea_s (slot-ordered edge attrs) directly.
__global__ void fill_kernel(const int* __restrict__ row, const int* __restrict__ col,
                            const int* __restrict__ starts, int* __restrict__ cnt,
                            const float* __restrict__ dinv, const float* __restrict__ ea,
                            int* __restrict__ src_s, float* __restrict__ w_s,
                            float4* __restrict__ ea_s) {
    int e = blockIdx.x * blockDim.x + threadIdx.x;
    if (e < Ee) {
        int c = col[e], r = row[e];
        float4 ev = *(const float4*)&ea[(size_t)e * 4];
        int slot = starts[c] + atomicAdd(&cnt[c], 1);
        src_s[slot] = r;
        w_s[slot] = dinv[r] * dinv[c];
        ea_s[slot] = ev;
    }
}

// x [N][7] -> padded aligned xp [N][8] (pad = 0); also zeroes the 16-entry
// src_s tail pad (hop v7 reads up to 3 slots past s1 without clamping).
__global__ void xpack_kernel(const float* __restrict__ x, float* __restrict__ xp,
                             int* __restrict__ srcpad) {
    int i = blockIdx.x * blockDim.x + threadIdx.x;
    if (i < 16) srcpad[i] = 0;
    if (i < Nn) {
        float4 a = make_float4(x[i * 7], x[i * 7 + 1], x[i * 7 + 2], x[i * 7 + 3]);
        float4 b = make_float4(x[i * 7 + 4], x[i * 7 + 5], x[i * 7 + 6], 0.0f);
        *(float4*)&xp[i * 8] = a;
        *(float4*)&xp[i * 8 + 4] = b;
    }
}

// Decoupled gather: xjs[slot] = xp[src_s[slot]] (32 B rows, slot-ordered out).
__global__ void xgather_kernel(const int* __restrict__ src_s, const float* __restrict__ xp,
                               float* __restrict__ xjs) {
    int gid = blockIdx.x * blockDim.x + threadIdx.x;
    int slot = gid >> 1, part = gid & 1;
    if (slot < Ee) {
        int src = src_s[slot];
        float4 v = *(const float4*)&xp[(size_t)src * 8 + part * 4];
        *(float4*)&xjs[(size_t)slot * 8 + part * 4] = v;
    }
}

// 17 weight matrices [k][n] fp32 -> FRAGMENT-SWIZZLED bf16 hi/lo planes.
__global__ void wconv_kernel(const float* __restrict__ eW2, const float* __restrict__ tagW,
                             unsigned short* __restrict__ WThi,
                             unsigned short* __restrict__ WTlo) {
    int id = blockIdx.x * blockDim.x + threadIdx.x;
    if (id >= 17 * 16384) return;
    int m = id >> 14;
    int rem = id & 16383;
    int n = rem >> 7, k = rem & 127;
    const float* src = (m == 0) ? eW2 : tagW + (size_t)(m - 1) * 16384;
    float f = src[k * Hd + n];
    unsigned h = bf16rne(f);
    float r = f - __uint_as_float(h << 16);
    int kc = k >> 5, quad = (k >> 3) & 3, j = k & 7;
    int nt = n >> 4, l15 = n & 15;
    int lane = quad * 16 + l15;
    int idx = (m << 14) + (((kc * 8 + nt) * 64) + lane) * 8 + j;
    WThi[idx] = (unsigned short)h;
    WTlo[idx] = (unsigned short)bf16rne(r);
}

// Layer-1-only edge pass v5: scalar (wave-uniform) loads as in v4, plus a
// 2-deep software pipeline on the slot-pair loads: the next pair's xjs/ea_s
// scalar loads are issued before consuming the current pair, hiding the
// ~300-cycle scalar-load latency under the FMA block. Math order identical.
__global__ __launch_bounds__(256) void edge_l1_kernel(
    const float* __restrict__ xp, const float* __restrict__ xjs,
    const float4* __restrict__ ea_s,
    const int* __restrict__ starts,
    const float* __restrict__ eW1, const float* __restrict__ eb1,
    unsigned short* __restrict__ tout) {
    int lane = threadIdx.x & 63;
    float w1x[18], w1y[18];
#pragma unroll
    for (int j = 0; j < 18; ++j) {
        w1x[j] = eW1[j * Hd + lane];
        w1y[j] = eW1[j * Hd + lane + 64];
    }
    float b1x = eb1[lane], b1y = eb1[lane + 64];
    int wid = __builtin_amdgcn_readfirstlane(
        (int)((blockIdx.x * 256u + threadIdx.x) >> 6));
    int nw = (gridDim.x * 256) >> 6;
    const float4* xjs4 = (const float4*)xjs;
    for (int node = wid; node < Nn; node += nw) {
        int s0 = starts[node], s1 = starts[node + 1];
        float4 p0 = *(const float4*)&xp[node * 8];
        float4 p1 = *(const float4*)&xp[node * 8 + 4];
        float prex = b1x + p0.x * w1x[0] + p0.y * w1x[1] + p0.z * w1x[2] + p0.w * w1x[3]
                   + p1.x * w1x[4] + p1.y * w1x[5] + p1.z * w1x[6];
        float prey = b1y + p0.x * w1y[0] + p0.y * w1y[1] + p0.z * w1y[2] + p0.w * w1y[3]
                   + p1.x * w1y[4] + p1.y * w1y[5] + p1.z * w1y[6];
        float accx = 0.0f, accy = 0.0f;
        int slot = s0;
        if (slot + 2 <= s1) {
            float4 A0 = xjs4[(size_t)slot * 2];
            float4 A1 = xjs4[(size_t)slot * 2 + 1];
            float4 B0 = xjs4[(size_t)slot * 2 + 2];
            float4 B1v = xjs4[(size_t)slot * 2 + 3];
            float4 EA = ea_s[slot], EB = ea_s[slot + 1];
            for (;;) {
                int ns = slot + 2;
                bool morep = (ns + 2 <= s1);
                float4 nA0, nA1, nB0, nB1, nEA, nEB;
                if (morep) {
                    nA0 = xjs4[(size_t)ns * 2];
                    nA1 = xjs4[(size_t)ns * 2 + 1];
                    nB0 = xjs4[(size_t)ns * 2 + 2];
                    nB1 = xjs4[(size_t)ns * 2 + 3];
                    nEA = ea_s[ns];
                    nEB = ea_s[ns + 1];
                }
                float u0 = prex + A0.x * w1x[7] + A0.y * w1x[8] + A0.z * w1x[9] + A0.w * w1x[10]
                         + A1.x * w1x[11] + A1.y * w1x[12] + A1.z * w1x[13]
                         + EA.x * w1x[14] + EA.y * w1x[15] + EA.z * w1x[16] + EA.w * w1x[17];
                float u1 = prey + A0.x * w1y[7] + A0.y * w1y[8] + A0.z * w1y[9] + A0.w * w1y[10]
                         + A1.x * w1y[11] + A1.y * w1y[12] + A1.z * w1y[13]
                         + EA.x * w1y[14] + EA.y * w1y[15] + EA.z * w1y[16] + EA.w * w1y[17];
                float v0 = prex + B0.x * w1x[7] + B0.y * w1x[8] + B0.z * w1x[9] + B0.w * w1x[10]
                         + B1v.x * w1x[11] + B1v.y * w1x[12] + B1v.z * w1x[13]
                         + EB.x * w1x[14] + EB.y * w1x[15] + EB.z * w1x[16] + EB.w * w1x[17];
                float v1 = prey + B0.x * w1y[7] + B0.y * w1y[8] + B0.z * w1y[9] + B0.w * w1y[10]
                         + B1v.x * w1y[11] + B1v.y * w1y[12] + B1v.z * w1y[13]
                         + EB.x * w1y[14] + EB.y * w1y[15] + EB.z * w1y[16] + EB.w * w1y[17];
                accx += fmaxf(u0, 0.0f) + fmaxf(v0, 0.0f);
                accy += fmaxf(u1, 0.0f) + fmaxf(v1, 0.0f);
                slot = ns;
                if (!morep) break;
                A0 = nA0; A1 = nA1; B0 = nB0; B1v = nB1; EA = nEA; EB = nEB;
            }
        }
        if (slot < s1) {
            float4 a0 = *(const float4*)&xjs[(size_t)slot * 8];
            float4 a1 = *(const float4*)&xjs[(size_t)slot * 8 + 4];
            float4 eA = ea_s[slot];
            float u0 = prex + a0.x * w1x[7] + a0.y * w1x[8] + a0.z * w1x[9] + a0.w * w1x[10]
                     + a1.x * w1x[11] + a1.y * w1x[12] + a1.z * w1x[13]
                     + eA.x * w1x[14] + eA.y * w1x[15] + eA.z * w1x[16] + eA.w * w1x[17];
            float u1 = prey + a0.x * w1y[7] + a0.y * w1y[8] + a0.z * w1y[9] + a0.w * w1y[10]
                     + a1.x * w1y[11] + a1.y * w1y[12] + a1.z * w1y[13]
                     + eA.x * w1y[14] + eA.y * w1y[15] + eA.z * w1y[16] + eA.w * w1y[17];
            accx += fmaxf(u0, 0.0f);
            accy += fmaxf(u1, 0.0f);
        }
        tout[node * Hd + lane] = (unsigned short)bf16rne(accx);
        tout[node * Hd + lane + 64] = (unsigned short)bf16rne(accy);
    }
}

// MFMA multi-source GEMM, all-bf16 A path (2 mfma/k-step uniform), LDS-free
// K-loop, fragment-swizzled W. Output is bf16 only (Cb16); when yout is
// non-null (final layer) the head y = C @ oW + ob is fused and Cb16 skipped.
__global__ __launch_bounds__(256, 2) void tag_gemm_mfma(
    const unsigned short* __restrict__ P0,
    const unsigned short* __restrict__ Pb1, const unsigned short* __restrict__ Pb2,
    const unsigned short* __restrict__ Pb3,
    const unsigned short* __restrict__ WThi, const unsigned short* __restrict__ WTlo,
    const float* __restrict__ bias, const int* __restrict__ rowdeg,
    unsigned short* __restrict__ Cb16,
    const float* __restrict__ oW, const float* __restrict__ ob,
    float* __restrict__ yout, int nsrc, int reluflag) {
    __shared__ float Cl[64 * 133];
    __shared__ float oWs[256];
    __shared__ float obs[2];
    const int tid = threadIdx.x;
    const int lane = tid & 63;
    const int wv = tid >> 6;
    const int l15 = lane & 15;
    const int quad = lane >> 4;
    const int rowbase = blockIdx.x * 64;
    const int arow = min(rowbase + wv * 16 + l15, Nn - 1);
    if (yout) {
        oWs[tid] = oW[tid & 255];
        if (tid < 2) obs[tid] = ob[tid];
    }

    float4v acc[8];
#pragma unroll
    for (int nt = 0; nt < 8; ++nt) acc[nt] = (float4v)0.0f;

#pragma unroll 1
    for (int g = 0; g < nsrc; ++g) {
        const unsigned short* Pb = (g == 0) ? P0 : (g == 1) ? Pb1 : (g == 2) ? Pb2 : Pb3;
        const unsigned short* Whg = WThi + (size_t)g * 16384;
        const unsigned short* Wlg = WTlo + (size_t)g * 16384;
#pragma unroll
        for (int kc = 0; kc < 4; ++kc) {
            U4 ab;
            ab.u = *(const uint4*)&Pb[(size_t)arow * Hd + kc * 32 + quad * 8];
            const unsigned short* whp = Whg + (size_t)(kc * 8) * 512 + lane * 8;
            const unsigned short* wlp = Wlg + (size_t)(kc * 8) * 512 + lane * 8;
#pragma unroll
            for (int nt = 0; nt < 8; ++nt) {
                U4 wh, wl;
                wh.u = *(const uint4*)&whp[nt * 512];
                wl.u = *(const uint4*)&wlp[nt * 512];
                acc[nt] = __builtin_amdgcn_mfma_f32_16x16x32_bf16(ab.s, wh.s, acc[nt], 0, 0, 0);
                acc[nt] = __builtin_amdgcn_mfma_f32_16x16x32_bf16(ab.s, wl.s, acc[nt], 0, 0, 0);
            }
        }
    }
#pragma unroll
    for (int nt = 0; nt < 8; ++nt)
#pragma unroll
        for (int reg = 0; reg < 4; ++reg)
            Cl[(wv * 16 + quad * 4 + reg) * 133 + nt * 16 + l15] = acc[nt][reg];
    __syncthreads();
#pragma unroll
    for (int i = 0; i < 8; ++i) {
        int s = tid + i * 256;
        int r = s >> 5, c4 = (s & 31) * 4;
        int grow = rowbase + r;
        if (grow < Nn) {
            float4 v = *(const float4*)&Cl[r * 133 + c4];
            float4 bv = *(const float4*)&bias[c4];
            float bs = rowdeg ? (float)rowdeg[grow] : 1.0f;
            v.x += bs * bv.x; v.y += bs * bv.y; v.z += bs * bv.z; v.w += bs * bv.w;
            if (reluflag) {
                v.x = fmaxf(v.x, 0.0f); v.y = fmaxf(v.y, 0.0f);
                v.z = fmaxf(v.z, 0.0f); v.w = fmaxf(v.w, 0.0f);
            }
            if (yout) {
                *(float4*)&Cl[r * 133 + c4] = v;  // keep for the fused head
            } else {
                uint2 p;
                p.x = bf16rne(v.x) | (bf16rne(v.y) << 16);
                p.y = bf16rne(v.z) | (bf16rne(v.w) << 16);
                *(uint2*)&Cb16[(size_t)grow * Hd + c4] = p;
            }
        }
    }
    if (yout) {
        __syncthreads();
        if (tid < 64) {
            int grow = rowbase + tid;
            if (grow < Nn) {
                float a0 = obs[0], a1 = obs[1];
#pragma unroll
                for (int c = 0; c < Hd; c += 4) {
                    float4 t = *(const float4*)&Cl[tid * 133 + c];
                    a0 += t.x * oWs[2 * c] + t.y * oWs[2 * c + 2]
                        + t.z * oWs[2 * c + 4] + t.w * oWs[2 * c + 6];
                    a1 += t.x * oWs[2 * c + 1] + t.y * oWs[2 * c + 3]
                        + t.z * oWs[2 * c + 5] + t.w * oWs[2 * c + 7];
                }
                *(float2*)&yout[(size_t)grow * 2] = make_float2(a0, a1);
            }
        }
    }
}

// bf16 hop v7: full-wave per slot, scalar src/w via uniform node, TRUE 4-deep
// gather pipeline. Gathers for 4 slot-groups (16 slots) are issued before the
// first consume; the steady loop is unrolled x4 over fixed register sets so
// refills stay 3-4 groups ahead with zero rotation moves. Tail groups use
// weight-zeroing (src_s padded by 16 zeroed entries) so loads stay contiguous
// and unclamped. Summation order identical to v6 (stream j = slots == j mod 4,
// groups in increasing base order, merge (a+b)+(c+d)).
__global__ __launch_bounds__(256) void hop_kernel(
    const unsigned short* __restrict__ pin, unsigned short* __restrict__ pout,
    const int* __restrict__ starts, const int* __restrict__ src_s,
    const float* __restrict__ w_s) {
    int lane = threadIdx.x & 63;
    int node = __builtin_amdgcn_readfirstlane(
        (int)((blockIdx.x * 256u + threadIdx.x) >> 6));
    if (node >= Nn) return;
    int s0 = starts[node], s1 = starts[node + 1];
    const unsigned* pin32 = (const unsigned*)pin;
    unsigned* pout32 = (unsigned*)pout;
    float a0 = 0.0f, a1 = 0.0f, b0 = 0.0f, b1 = 0.0f;
    float c0 = 0.0f, c1 = 0.0f, d0 = 0.0f, d1 = 0.0f;
    if (s1 > s0) {
#define HLOAD(B, W0, W1, W2, W3, V0, V1, V2, V3)                        \
        if ((B) < s1) {                                                 \
            int _r0 = src_s[(B)], _r1 = src_s[(B) + 1];                 \
            int _r2 = src_s[(B) + 2], _r3 = src_s[(B) + 3];             \
            W0 = w_s[(B)];                                              \
            W1 = ((B) + 1 < s1) ? w_s[(B) + 1] : 0.0f;                  \
            W2 = ((B) + 2 < s1) ? w_s[(B) + 2] : 0.0f;                  \
            W3 = ((B) + 3 < s1) ? w_s[(B) + 3] : 0.0f;                  \
            V0 = pin32[(size_t)_r0 * 64 + lane];                        \
            V1 = pin32[(size_t)_r1 * 64 + lane];                        \
            V2 = pin32[(size_t)_r2 * 64 + lane];                        \
            V3 = pin32[(size_t)_r3 * 64 + lane];                        \
        } else {                                                        \
            W0 = W1 = W2 = W3 = 0.0f;                                   \
            V0 = V1 = V2 = V3 = 0u;                                     \
        }
#define HCONS(W0, W1, W2, W3, V0, V1, V2, V3)                           \
        a0 += W0 * bf16lo(V0); a1 += W0 * bf16hi(V0);                   \
        b0 += W1 * bf16lo(V1); b1 += W1 * bf16hi(V1);                   \
        c0 += W2 * bf16lo(V2); c1 += W2 * bf16hi(V2);                   \
        d0 += W3 * bf16lo(V3); d1 += W3 * bf16hi(V3);
        float wA0, wA1, wA2, wA3, wB0, wB1, wB2, wB3;
        float wC0, wC1, wC2, wC3, wD0, wD1, wD2, wD3;
        unsigned vA0, vA1, vA2, vA3, vB0, vB1, vB2, vB3;
        unsigned vC0, vC1, vC2, vC3, vD0, vD1, vD2, vD3;
        HLOAD(s0, wA0, wA1, wA2, wA3, vA0, vA1, vA2, vA3);
        HLOAD(s0 + 4, wB0, wB1, wB2, wB3, vB0, vB1, vB2, vB3);
        HLOAD(s0 + 8, wC0, wC1, wC2, wC3, vC0, vC1, vC2, vC3);
        HLOAD(s0 + 12, wD0, wD1, wD2, wD3, vD0, vD1, vD2, vD3);
        int base = s0;
        for (;;) {
            HCONS(wA0, wA1, wA2, wA3, vA0, vA1, vA2, vA3);
            if (base + 4 >= s1) break;
            HLOAD(base + 16, wA0, wA1, wA2, wA3, vA0, vA1, vA2, vA3);
            base += 4;
            HCONS(wB0, wB1, wB2, wB3, vB0, vB1, vB2, vB3);
            if (base + 4 >= s1) break;
            HLOAD(base + 16, wB0, wB1, wB2, wB3, vB0, vB1, vB2, vB3);
            base += 4;
            HCONS(wC0, wC1, wC2, wC3, vC0, vC1, vC2, vC3);
            if (base + 4 >= s1) break;
            HLOAD(base + 16, wC0, wC1, wC2, wC3, vC0, vC1, vC2, vC3);
            base += 4;
            HCONS(wD0, wD1, wD2, wD3, vD0, vD1, vD2, vD3);
            if (base + 4 >= s1) break;
            HLOAD(base + 16, wD0, wD1, wD2, wD3, vD0, vD1, vD2, vD3);
            base += 4;
        }
#undef HLOAD
#undef HCONS
    }
    float m0 = (a0 + b0) + (c0 + d0);
    float m1 = (a1 + b1) + (c1 + d1);
    unsigned o = bf16rne(m0) | (bf16rne(m1) << 16);
    pout32[(size_t)node * 64 + lane] = o;
}

extern "C" void kernel_launch(void* const* d_in, const int* in_sizes, int n_in,
                              void* d_out, int out_size, void* d_ws, size_t ws_size,
                              hipStream_t stream) {
    const float* x    = (const float*)d_in[0];
    const int*   ei   = (const int*)d_in[1];
    const float* ea   = (const float*)d_in[2];
    const float* eW1  = (const float*)d_in[3];
    const float* eb1  = (const float*)d_in[4];
    const float* eW2  = (const float*)d_in[5];
    const float* eb2  = (const float*)d_in[6];
    const float* tagW = (const float*)d_in[7];
    const float* tagb = (const float*)d_in[8];
    const float* oW   = (const float*)d_in[9];
    const float* ob   = (const float*)d_in[10];
    float* y = (float*)d_out;
    const int* row = ei;        // source
    const int* col = ei + Ee;   // target

    char* wp = (char*)d_ws;
    auto carve = [&](size_t bytes) -> char* {
        char* p = wp;
        wp += (bytes + 15) & ~(size_t)15;
        return p;
    };
    int* deg     = (int*)carve((size_t)2 * Nn * 4);
    int* cnt     = deg + Nn;
    int* starts  = (int*)carve((size_t)(Nn + 1) * 4);
    float* dinv  = (float*)carve((size_t)Nn * 4);
    int* src_s   = (int*)carve((size_t)(Ee + 16) * 4);   // +16 pad (zeroed)
    float* w_s   = (float*)carve((size_t)(Ee + 16) * 4); // +16 pad (never used)
    float4* ea_s = (float4*)carve((size_t)Ee * 16);
    unsigned short* WThi = (unsigned short*)carve((size_t)17 * 16384 * 2);
    unsigned short* WTlo = (unsigned short*)carve((size_t)17 * 16384 * 2);
    unsigned short* t16  = (unsigned short*)carve((size_t)Nn * Hd * 2);
    unsigned short* h16a = (unsigned short*)carve((size_t)Nn * Hd * 2);
    unsigned short* h16b = (unsigned short*)carve((size_t)Nn * Hd * 2);
    unsigned short* pb0  = (unsigned short*)carve((size_t)Nn * Hd * 2);
    unsigned short* pb1  = (unsigned short*)carve((size_t)Nn * Hd * 2);
    unsigned short* pb2  = (unsigned short*)carve((size_t)Nn * Hd * 2);
    // aliases (dead before their regions are first written):
    float* xp  = (float*)pb2;   // 1.6 MB; pb2 first written at hop k=3
    float* xjs = (float*)h16b;  // 19.2 MB spans h16b+pb0; first written layer-0 gemm/hop

    zero_int_kernel<<<400, 256, 0, stream>>>(deg, 2 * Nn);
    count_kernel<<<(Ee + 255) / 256, 256, 0, stream>>>(col, deg);
    wconv_kernel<<<(17 * 16384 + 255) / 256, 256, 0, stream>>>(eW2, tagW, WThi, WTlo);
    xpack_kernel<<<(Nn + 255) / 256, 256, 0, stream>>>(x, xp, src_s + Ee);
    scan_kernel<<<1, 1024, 0, stream>>>(deg, starts, dinv);
    fill_kernel<<<(Ee + 255) / 256, 256, 0, stream>>>(row, col, starts, cnt, dinv, ea,
                                                      src_s, w_s, ea_s);
    xgather_kernel<<<(2 * Ee + 255) / 256, 256, 0, stream>>>(src_s, xp, xjs);
    // t = per-target sum of relu(layer1), bf16 (into t16)
    edge_l1_kernel<<<6250, 256, 0, stream>>>(xp, xjs, ea_s, starts, eW1, eb1, t16);
    // h0 = t @ W2 + deg*b2  (bf16 into h16a)
    const int gemm_grid = (Nn + 63) / 64;
    tag_gemm_mfma<<<gemm_grid, 256, 0, stream>>>(t16, nullptr, nullptr, nullptr,
                                                 WThi, WTlo, eb2, deg, h16a,
                                                 nullptr, nullptr, nullptr, 1, 0);

    unsigned short* hin = h16a;
    unsigned short* hout = h16b;
    for (int l = 0; l < Ld; ++l) {
        hop_kernel<<<12500, 256, 0, stream>>>(hin, pb0, starts, src_s, w_s);
        hop_kernel<<<12500, 256, 0, stream>>>(pb0, pb1, starts, src_s, w_s);
        hop_kernel<<<12500, 256, 0, stream>>>(pb1, pb2, starts, src_s, w_s);
        int last = (l == Ld - 1);
        tag_gemm_mfma<<<gemm_grid, 256, 0, stream>>>(
            hin, pb0, pb1, pb2,
            WThi + (size_t)(1 + l * 4) * 16384, WTlo + (size_t)(1 + l * 4) * 16384,
            tagb + l * Hd, nullptr, last ? nullptr : hout,
            last ? oW : nullptr, last ? ob : nullptr, last ? y : nullptr,
            4, last ? 0 : 1);
        unsigned short* t = hin; hin = hout; hout = t;
    }
}

// Round 3
// 725.487 us; speedup vs baseline: 1.1576x; 1.0643x over previous
//
#include <hip/hip_runtime.h>

#define Nn 50000
#define Ee 600000
#define Hd 128
#define Ld 4
#define Kd 3

typedef __attribute__((ext_vector_type(8))) short short8;
typedef __attribute__((ext_vector_type(4))) float float4v;

union U4 { uint4 u; short8 s; };

__device__ __forceinline__ unsigned bf16rne(float f) {
    unsigned u = __float_as_uint(f);
    return (u + 0x7fffu + ((u >> 16) & 1u)) >> 16;
}
__device__ __forceinline__ float bf16lo(unsigned v) { return __uint_as_float(v << 16); }
__device__ __forceinline__ float bf16hi(unsigned v) { return __uint_as_float(v & 0xffff0000u); }

__global__ void zero_int_kernel(int* __restrict__ p, int n) {
    int i = blockIdx.x * blockDim.x + threadIdx.x;
    int stride = gridDim.x * blockDim.x;
    for (; i < n; i += stride) p[i] = 0;
}

__global__ void count_kernel(const int* __restrict__ col, int* __restrict__ deg) {
    int e = blockIdx.x * blockDim.x + threadIdx.x;
    if (e < Ee) atomicAdd(&deg[col[e]], 1);
}

// --- Parallel scan, phase A: per-block (1024) sums of deg; also emits dinv. ---
__global__ __launch_bounds__(1024) void scan_bsums_kernel(const int* __restrict__ deg,
                                                          int* __restrict__ bsum,
                                                          float* __restrict__ dinv) {
    __shared__ int ws[16];
    int i = blockIdx.x * 1024 + threadIdx.x;
    int v = (i < Nn) ? deg[i] : 0;
    if (i < Nn) dinv[i] = (v > 0) ? rsqrtf((float)v) : 0.0f;
    int lane = threadIdx.x & 63, w = threadIdx.x >> 6;
    int s = v;
#pragma unroll
    for (int off = 32; off >= 1; off >>= 1) s += __shfl_xor(s, off);
    if (lane == 0) ws[w] = s;
    __syncthreads();
    if (threadIdx.x < 16) {
        int p = ws[threadIdx.x];
#pragma unroll
        for (int off = 8; off >= 1; off >>= 1) p += __shfl_xor(p, off);
        if (threadIdx.x == 0) bsum[blockIdx.x] = p;
    }
}

// --- Phase B: single-wave exclusive scan of the 49 block sums. ---
__global__ void scan_boff_kernel(const int* __restrict__ bsum, int* __restrict__ boff,
                                 int* __restrict__ starts) {
    int lane = threadIdx.x;  // 64 threads
    int v = (lane < 49) ? bsum[lane] : 0;
    int s = v;
#pragma unroll
    for (int off = 1; off < 64; off <<= 1) {
        int t = __shfl_up(s, off);
        if (lane >= off) s += t;
    }
    if (lane < 49) boff[lane] = s - v;
    if (lane == 63) starts[Nn] = s;  // grand total
}

// --- Phase C: block-local exclusive scan + block offset -> starts. ---
__global__ __launch_bounds__(1024) void scan_final_kernel(const int* __restrict__ deg,
                                                          const int* __restrict__ boff,
                                                          int* __restrict__ starts) {
    __shared__ int wsum[16];
    int tid = threadIdx.x;
    int lane = tid & 63, w = tid >> 6;
    int i = blockIdx.x * 1024 + tid;
    int v = (i < Nn) ? deg[i] : 0;
    int s = v;
#pragma unroll
    for (int off = 1; off < 64; off <<= 1) {
        int t = __shfl_up(s, off);
        if (lane >= off) s += t;
    }
    if (lane == 63) wsum[w] = s;
    __syncthreads();
    if (w == 0) {
        int ws2 = (lane < 16) ? wsum[lane] : 0;
#pragma unroll
        for (int off = 1; off < 16; off <<= 1) {
            int t = __shfl_up(ws2, off);
            if (lane >= off) ws2 += t;
        }
        if (lane < 16) wsum[lane] = ws2;
    }
    __syncthreads();
    int woff = (w > 0) ? wsum[w - 1] : 0;
    if (i < Nn) starts[i] = boff[blockIdx.x] + woff + s - v;
}

// CSR fill; writes ea_s (slot-ordered edge attrs) directly.
__global__ void fill_kernel(const int* __restrict__ row, const int* __restrict__ col,
                            const int* __restrict__ starts, int* __restrict__ cnt,
                            const float* __restrict__ dinv, const float* __restrict__ ea,
                            int* __restrict__ src_s, float* __restrict__ w_s,
                            float4* __restrict__ ea_s) {
    int e = blockIdx.x * blockDim.x + threadIdx.x;
    if (e < Ee) {
        int c = col[e], r = row[e];
        float4 ev = *(const float4*)&ea[(size_t)e * 4];
        int slot = starts[c] + atomicAdd(&cnt[c], 1);
        src_s[slot] = r;
        w_s[slot] = dinv[r] * dinv[c];
        ea_s[slot] = ev;
    }
}

// x [N][7] -> padded aligned xp [N][8] (pad = 0); also zeroes the 64-entry
// src_s tail pad (hop v8 reads up to 23 slots past s1 without clamping).
__global__ void xpack_kernel(const float* __restrict__ x, float* __restrict__ xp,
                             int* __restrict__ srcpad) {
    int i = blockIdx.x * blockDim.x + threadIdx.x;
    if (i < 64) srcpad[i] = 0;
    if (i < Nn) {
        float4 a = make_float4(x[i * 7], x[i * 7 + 1], x[i * 7 + 2], x[i * 7 + 3]);
        float4 b = make_float4(x[i * 7 + 4], x[i * 7 + 5], x[i * 7 + 6], 0.0f);
        *(float4*)&xp[i * 8] = a;
        *(float4*)&xp[i * 8 + 4] = b;
    }
}

// Decoupled gather: xjs[slot] = xp[src_s[slot]] (32 B rows, slot-ordered out).
__global__ void xgather_kernel(const int* __restrict__ src_s, const float* __restrict__ xp,
                               float* __restrict__ xjs) {
    int gid = blockIdx.x * blockDim.x + threadIdx.x;
    int slot = gid >> 1, part = gid & 1;
    if (slot < Ee) {
        int src = src_s[slot];
        float4 v = *(const float4*)&xp[(size_t)src * 8 + part * 4];
        *(float4*)&xjs[(size_t)slot * 8 + part * 4] = v;
    }
}

// 17 weight matrices [k][n] fp32 -> FRAGMENT-SWIZZLED bf16 hi/lo planes.
__global__ void wconv_kernel(const float* __restrict__ eW2, const float* __restrict__ tagW,
                             unsigned short* __restrict__ WThi,
                             unsigned short* __restrict__ WTlo) {
    int id = blockIdx.x * blockDim.x + threadIdx.x;
    if (id >= 17 * 16384) return;
    int m = id >> 14;
    int rem = id & 16383;
    int n = rem >> 7, k = rem & 127;
    const float* src = (m == 0) ? eW2 : tagW + (size_t)(m - 1) * 16384;
    float f = src[k * Hd + n];
    unsigned h = bf16rne(f);
    float r = f - __uint_as_float(h << 16);
    int kc = k >> 5, quad = (k >> 3) & 3, j = k & 7;
    int nt = n >> 4, l15 = n & 15;
    int lane = quad * 16 + l15;
    int idx = (m << 14) + (((kc * 8 + nt) * 64) + lane) * 8 + j;
    WThi[idx] = (unsigned short)h;
    WTlo[idx] = (unsigned short)bf16rne(r);
}

// Layer-1-only edge pass v5: scalar (wave-uniform) loads, 2-deep pair pipeline.
__global__ __launch_bounds__(256) void edge_l1_kernel(
    const float* __restrict__ xp, const float* __restrict__ xjs,
    const float4* __restrict__ ea_s,
    const int* __restrict__ starts,
    const float* __restrict__ eW1, const float* __restrict__ eb1,
    unsigned short* __restrict__ tout) {
    int lane = threadIdx.x & 63;
    float w1x[18], w1y[18];
#pragma unroll
    for (int j = 0; j < 18; ++j) {
        w1x[j] = eW1[j * Hd + lane];
        w1y[j] = eW1[j * Hd + lane + 64];
    }
    float b1x = eb1[lane], b1y = eb1[lane + 64];
    int wid = __builtin_amdgcn_readfirstlane(
        (int)((blockIdx.x * 256u + threadIdx.x) >> 6));
    int nw = (gridDim.x * 256) >> 6;
    const float4* xjs4 = (const float4*)xjs;
    for (int node = wid; node < Nn; node += nw) {
        int s0 = starts[node], s1 = starts[node + 1];
        float4 p0 = *(const float4*)&xp[node * 8];
        float4 p1 = *(const float4*)&xp[node * 8 + 4];
        float prex = b1x + p0.x * w1x[0] + p0.y * w1x[1] + p0.z * w1x[2] + p0.w * w1x[3]
                   + p1.x * w1x[4] + p1.y * w1x[5] + p1.z * w1x[6];
        float prey = b1y + p0.x * w1y[0] + p0.y * w1y[1] + p0.z * w1y[2] + p0.w * w1y[3]
                   + p1.x * w1y[4] + p1.y * w1y[5] + p1.z * w1y[6];
        float accx = 0.0f, accy = 0.0f;
        int slot = s0;
        if (slot + 2 <= s1) {
            float4 A0 = xjs4[(size_t)slot * 2];
            float4 A1 = xjs4[(size_t)slot * 2 + 1];
            float4 B0 = xjs4[(size_t)slot * 2 + 2];
            float4 B1v = xjs4[(size_t)slot * 2 + 3];
            float4 EA = ea_s[slot], EB = ea_s[slot + 1];
            for (;;) {
                int ns = slot + 2;
                bool morep = (ns + 2 <= s1);
                float4 nA0, nA1, nB0, nB1, nEA, nEB;
                if (morep) {
                    nA0 = xjs4[(size_t)ns * 2];
                    nA1 = xjs4[(size_t)ns * 2 + 1];
                    nB0 = xjs4[(size_t)ns * 2 + 2];
                    nB1 = xjs4[(size_t)ns * 2 + 3];
                    nEA = ea_s[ns];
                    nEB = ea_s[ns + 1];
                }
                float u0 = prex + A0.x * w1x[7] + A0.y * w1x[8] + A0.z * w1x[9] + A0.w * w1x[10]
                         + A1.x * w1x[11] + A1.y * w1x[12] + A1.z * w1x[13]
                         + EA.x * w1x[14] + EA.y * w1x[15] + EA.z * w1x[16] + EA.w * w1x[17];
                float u1 = prey + A0.x * w1y[7] + A0.y * w1y[8] + A0.z * w1y[9] + A0.w * w1y[10]
                         + A1.x * w1y[11] + A1.y * w1y[12] + A1.z * w1y[13]
                         + EA.x * w1y[14] + EA.y * w1y[15] + EA.z * w1y[16] + EA.w * w1y[17];
                float v0 = prex + B0.x * w1x[7] + B0.y * w1x[8] + B0.z * w1x[9] + B0.w * w1x[10]
                         + B1v.x * w1x[11] + B1v.y * w1x[12] + B1v.z * w1x[13]
                         + EB.x * w1x[14] + EB.y * w1x[15] + EB.z * w1x[16] + EB.w * w1x[17];
                float v1 = prey + B0.x * w1y[7] + B0.y * w1y[8] + B0.z * w1y[9] + B0.w * w1y[10]
                         + B1v.x * w1y[11] + B1v.y * w1y[12] + B1v.z * w1y[13]
                         + EB.x * w1y[14] + EB.y * w1y[15] + EB.z * w1y[16] + EB.w * w1y[17];
                accx += fmaxf(u0, 0.0f) + fmaxf(v0, 0.0f);
                accy += fmaxf(u1, 0.0f) + fmaxf(v1, 0.0f);
                slot = ns;
                if (!morep) break;
                A0 = nA0; A1 = nA1; B0 = nB0; B1v = nB1; EA = nEA; EB = nEB;
            }
        }
        if (slot < s1) {
            float4 a0 = *(const float4*)&xjs[(size_t)slot * 8];
            float4 a1 = *(const float4*)&xjs[(size_t)slot * 8 + 4];
            float4 eA = ea_s[slot];
            float u0 = prex + a0.x * w1x[7] + a0.y * w1x[8] + a0.z * w1x[9] + a0.w * w1x[10]
                     + a1.x * w1x[11] + a1.y * w1x[12] + a1.z * w1x[13]
                     + eA.x * w1x[14] + eA.y * w1x[15] + eA.z * w1x[16] + eA.w * w1x[17];
            float u1 = prey + a0.x * w1y[7] + a0.y * w1y[8] + a0.z * w1y[9] + a0.w * w1y[10]
                     + a1.x * w1y[11] + a1.y * w1y[12] + a1.z * w1y[13]
                     + eA.x * w1y[14] + eA.y * w1y[15] + eA.z * w1y[16] + eA.w * w1y[17];
            accx += fmaxf(u0, 0.0f);
            accy += fmaxf(u1, 0.0f);
        }
        tout[node * Hd + lane] = (unsigned short)bf16rne(accx);
        tout[node * Hd + lane + 64] = (unsigned short)bf16rne(accy);
    }
}

// MFMA multi-source GEMM, all-bf16 A path (2 mfma/k-step uniform), LDS-free
// K-loop, fragment-swizzled W. Output is bf16 only (Cb16); when yout is
// non-null (final layer) the head y = C @ oW + ob is fused and Cb16 skipped.
__global__ __launch_bounds__(256, 2) void tag_gemm_mfma(
    const unsigned short* __restrict__ P0,
    const unsigned short* __restrict__ Pb1, const unsigned short* __restrict__ Pb2,
    const unsigned short* __restrict__ Pb3,
    const unsigned short* __restrict__ WThi, const unsigned short* __restrict__ WTlo,
    const float* __restrict__ bias, const int* __restrict__ rowdeg,
    unsigned short* __restrict__ Cb16,
    const float* __restrict__ oW, const float* __restrict__ ob,
    float* __restrict__ yout, int nsrc, int reluflag) {
    __shared__ float Cl[64 * 133];
    __shared__ float oWs[256];
    __shared__ float obs[2];
    const int tid = threadIdx.x;
    const int lane = tid & 63;
    const int wv = tid >> 6;
    const int l15 = lane & 15;
    const int quad = lane >> 4;
    const int rowbase = blockIdx.x * 64;
    const int arow = min(rowbase + wv * 16 + l15, Nn - 1);
    if (yout) {
        oWs[tid] = oW[tid & 255];
        if (tid < 2) obs[tid] = ob[tid];
    }

    float4v acc[8];
#pragma unroll
    for (int nt = 0; nt < 8; ++nt) acc[nt] = (float4v)0.0f;

#pragma unroll 1
    for (int g = 0; g < nsrc; ++g) {
        const unsigned short* Pb = (g == 0) ? P0 : (g == 1) ? Pb1 : (g == 2) ? Pb2 : Pb3;
        const unsigned short* Whg = WThi + (size_t)g * 16384;
        const unsigned short* Wlg = WTlo + (size_t)g * 16384;
#pragma unroll
        for (int kc = 0; kc < 4; ++kc) {
            U4 ab;
            ab.u = *(const uint4*)&Pb[(size_t)arow * Hd + kc * 32 + quad * 8];
            const unsigned short* whp = Whg + (size_t)(kc * 8) * 512 + lane * 8;
            const unsigned short* wlp = Wlg + (size_t)(kc * 8) * 512 + lane * 8;
#pragma unroll
            for (int nt = 0; nt < 8; ++nt) {
                U4 wh, wl;
                wh.u = *(const uint4*)&whp[nt * 512];
                wl.u = *(const uint4*)&wlp[nt * 512];
                acc[nt] = __builtin_amdgcn_mfma_f32_16x16x32_bf16(ab.s, wh.s, acc[nt], 0, 0, 0);
                acc[nt] = __builtin_amdgcn_mfma_f32_16x16x32_bf16(ab.s, wl.s, acc[nt], 0, 0, 0);
            }
        }
    }
#pragma unroll
    for (int nt = 0; nt < 8; ++nt)
#pragma unroll
        for (int reg = 0; reg < 4; ++reg)
            Cl[(wv * 16 + quad * 4 + reg) * 133 + nt * 16 + l15] = acc[nt][reg];
    __syncthreads();
#pragma unroll
    for (int i = 0; i < 8; ++i) {
        int s = tid + i * 256;
        int r = s >> 5, c4 = (s & 31) * 4;
        int grow = rowbase + r;
        if (grow < Nn) {
            float4 v = *(const float4*)&Cl[r * 133 + c4];
            float4 bv = *(const float4*)&bias[c4];
            float bs = rowdeg ? (float)rowdeg[grow] : 1.0f;
            v.x += bs * bv.x; v.y += bs * bv.y; v.z += bs * bv.z; v.w += bs * bv.w;
            if (reluflag) {
                v.x = fmaxf(v.x, 0.0f); v.y = fmaxf(v.y, 0.0f);
                v.z = fmaxf(v.z, 0.0f); v.w = fmaxf(v.w, 0.0f);
            }
            if (yout) {
                *(float4*)&Cl[r * 133 + c4] = v;  // keep for the fused head
            } else {
                uint2 p;
                p.x = bf16rne(v.x) | (bf16rne(v.y) << 16);
                p.y = bf16rne(v.z) | (bf16rne(v.w) << 16);
                *(uint2*)&Cb16[(size_t)grow * Hd + c4] = p;
            }
        }
    }
    if (yout) {
        __syncthreads();
        if (tid < 64) {
            int grow = rowbase + tid;
            if (grow < Nn) {
                float a0 = obs[0], a1 = obs[1];
#pragma unroll
                for (int c = 0; c < Hd; c += 4) {
                    float4 t = *(const float4*)&Cl[tid * 133 + c];
                    a0 += t.x * oWs[2 * c] + t.y * oWs[2 * c + 2]
                        + t.z * oWs[2 * c + 4] + t.w * oWs[2 * c + 6];
                    a1 += t.x * oWs[2 * c + 1] + t.y * oWs[2 * c + 3]
                        + t.z * oWs[2 * c + 5] + t.w * oWs[2 * c + 7];
                }
                *(float2*)&yout[(size_t)grow * 2] = make_float2(a0, a1);
            }
        }
    }
}

// bf16 hop v8: ALL src/w scalar loads hoisted to node entry (covers deg<=24,
// ~99.9% of nodes; one lgkmcnt wait per node), then all gathers issued
// back-to-back, then consume. Rare deg>24 tail = sequential 4-slot groups.
// Stream assignment (slot == j mod 4) and merge (a+b)+(c+d) identical to v7.
// src_s/w_s padded by 64 entries (src pad zeroed) so loads never clamp.
__global__ __launch_bounds__(256) void hop_kernel(
    const unsigned short* __restrict__ pin, unsigned short* __restrict__ pout,
    const int* __restrict__ starts, const int* __restrict__ src_s,
    const float* __restrict__ w_s) {
    int lane = threadIdx.x & 63;
    int node = __builtin_amdgcn_readfirstlane(
        (int)((blockIdx.x * 256u + threadIdx.x) >> 6));
    if (node >= Nn) return;
    int s0 = starts[node], s1 = starts[node + 1];
    int deg = s1 - s0;
    const unsigned* pin32 = (const unsigned*)pin;
    unsigned* pout32 = (unsigned*)pout;
    float a0 = 0.0f, a1 = 0.0f, b0 = 0.0f, b1 = 0.0f;
    float c0 = 0.0f, c1 = 0.0f, d0 = 0.0f, d1 = 0.0f;
    if (deg > 0) {
        int sv[24];
        float wv[24];
#pragma unroll
        for (int j = 0; j < 24; ++j) sv[j] = src_s[s0 + j];
#pragma unroll
        for (int j = 0; j < 24; ++j) wv[j] = w_s[s0 + j];
        unsigned vv[24];
        // issue phase: all gathers for live groups, no consumes in between
#pragma unroll
        for (int g = 0; g < 6; ++g) {
            if (g * 4 < deg) {
#pragma unroll
                for (int j = 0; j < 4; ++j)
                    vv[g * 4 + j] = pin32[(size_t)sv[g * 4 + j] * 64 + lane];
            }
        }
        // consume phase
#pragma unroll
        for (int g = 0; g < 6; ++g) {
            if (g * 4 < deg) {
                float w0 = wv[g * 4];
                float w1 = (g * 4 + 1 < deg) ? wv[g * 4 + 1] : 0.0f;
                float w2 = (g * 4 + 2 < deg) ? wv[g * 4 + 2] : 0.0f;
                float w3 = (g * 4 + 3 < deg) ? wv[g * 4 + 3] : 0.0f;
                a0 += w0 * bf16lo(vv[g * 4]);     a1 += w0 * bf16hi(vv[g * 4]);
                b0 += w1 * bf16lo(vv[g * 4 + 1]); b1 += w1 * bf16hi(vv[g * 4 + 1]);
                c0 += w2 * bf16lo(vv[g * 4 + 2]); c1 += w2 * bf16hi(vv[g * 4 + 2]);
                d0 += w3 * bf16lo(vv[g * 4 + 3]); d1 += w3 * bf16hi(vv[g * 4 + 3]);
            }
        }
        if (deg > 24) {
            for (int base = s0 + 24; base < s1; base += 4) {
                int r0 = src_s[base], r1 = src_s[base + 1];
                int r2 = src_s[base + 2], r3 = src_s[base + 3];
                float w0 = w_s[base];
                float w1 = (base + 1 < s1) ? w_s[base + 1] : 0.0f;
                float w2 = (base + 2 < s1) ? w_s[base + 2] : 0.0f;
                float w3 = (base + 3 < s1) ? w_s[base + 3] : 0.0f;
                unsigned v0 = pin32[(size_t)r0 * 64 + lane];
                unsigned v1 = pin32[(size_t)r1 * 64 + lane];
                unsigned v2 = pin32[(size_t)r2 * 64 + lane];
                unsigned v3 = pin32[(size_t)r3 * 64 + lane];
                a0 += w0 * bf16lo(v0); a1 += w0 * bf16hi(v0);
                b0 += w1 * bf16lo(v1); b1 += w1 * bf16hi(v1);
                c0 += w2 * bf16lo(v2); c1 += w2 * bf16hi(v2);
                d0 += w3 * bf16lo(v3); d1 += w3 * bf16hi(v3);
            }
        }
    }
    float m0 = (a0 + b0) + (c0 + d0);
    float m1 = (a1 + b1) + (c1 + d1);
    unsigned o = bf16rne(m0) | (bf16rne(m1) << 16);
    pout32[(size_t)node * 64 + lane] = o;
}

extern "C" void kernel_launch(void* const* d_in, const int* in_sizes, int n_in,
                              void* d_out, int out_size, void* d_ws, size_t ws_size,
                              hipStream_t stream) {
    const float* x    = (const float*)d_in[0];
    const int*   ei   = (const int*)d_in[1];
    const float* ea   = (const float*)d_in[2];
    const float* eW1  = (const float*)d_in[3];
    const float* eb1  = (const float*)d_in[4];
    const float* eW2  = (const float*)d_in[5];
    const float* eb2  = (const float*)d_in[6];
    const float* tagW = (const float*)d_in[7];
    const float* tagb = (const float*)d_in[8];
    const float* oW   = (const float*)d_in[9];
    const float* ob   = (const float*)d_in[10];
    float* y = (float*)d_out;
    const int* row = ei;        // source
    const int* col = ei + Ee;   // target

    char* wp = (char*)d_ws;
    auto carve = [&](size_t bytes) -> char* {
        char* p = wp;
        wp += (bytes + 15) & ~(size_t)15;
        return p;
    };
    int* deg     = (int*)carve((size_t)2 * Nn * 4);
    int* cnt     = deg + Nn;
    int* starts  = (int*)carve((size_t)(Nn + 1) * 4);
    float* dinv  = (float*)carve((size_t)Nn * 4);
    int* bsum    = (int*)carve((size_t)64 * 4);
    int* boff    = (int*)carve((size_t)64 * 4);
    int* src_s   = (int*)carve((size_t)(Ee + 64) * 4);   // +64 pad (zeroed)
    float* w_s   = (float*)carve((size_t)(Ee + 64) * 4); // +64 pad (never consumed)
    float4* ea_s = (float4*)carve((size_t)Ee * 16);
    unsigned short* WThi = (unsigned short*)carve((size_t)17 * 16384 * 2);
    unsigned short* WTlo = (unsigned short*)carve((size_t)17 * 16384 * 2);
    unsigned short* t16  = (unsigned short*)carve((size_t)Nn * Hd * 2);
    unsigned short* h16a = (unsigned short*)carve((size_t)Nn * Hd * 2);
    unsigned short* h16b = (unsigned short*)carve((size_t)Nn * Hd * 2);
    unsigned short* pb0  = (unsigned short*)carve((size_t)Nn * Hd * 2);
    unsigned short* pb1  = (unsigned short*)carve((size_t)Nn * Hd * 2);
    unsigned short* pb2  = (unsigned short*)carve((size_t)Nn * Hd * 2);
    // aliases (dead before their regions are first written):
    float* xp  = (float*)pb2;   // 1.6 MB; pb2 first written at hop k=3
    float* xjs = (float*)h16b;  // 19.2 MB spans h16b+pb0; first written layer-0 gemm/hop

    const int scan_blocks = (Nn + 1023) / 1024;  // 49

    zero_int_kernel<<<400, 256, 0, stream>>>(deg, 2 * Nn);
    count_kernel<<<(Ee + 255) / 256, 256, 0, stream>>>(col, deg);
    wconv_kernel<<<(17 * 16384 + 255) / 256, 256, 0, stream>>>(eW2, tagW, WThi, WTlo);
    xpack_kernel<<<(Nn + 255) / 256, 256, 0, stream>>>(x, xp, src_s + Ee);
    scan_bsums_kernel<<<scan_blocks, 1024, 0, stream>>>(deg, bsum, dinv);
    scan_boff_kernel<<<1, 64, 0, stream>>>(bsum, boff, starts);
    scan_final_kernel<<<scan_blocks, 1024, 0, stream>>>(deg, boff, starts);
    fill_kernel<<<(Ee + 255) / 256, 256, 0, stream>>>(row, col, starts, cnt, dinv, ea,
                                                      src_s, w_s, ea_s);
    xgather_kernel<<<(2 * Ee + 255) / 256, 256, 0, stream>>>(src_s, xp, xjs);
    // t = per-target sum of relu(layer1), bf16 (into t16)
    edge_l1_kernel<<<6250, 256, 0, stream>>>(xp, xjs, ea_s, starts, eW1, eb1, t16);
    // h0 = t @ W2 + deg*b2  (bf16 into h16a)
    const int gemm_grid = (Nn + 63) / 64;
    tag_gemm_mfma<<<gemm_grid, 256, 0, stream>>>(t16, nullptr, nullptr, nullptr,
                                                 WThi, WTlo, eb2, deg, h16a,
                                                 nullptr, nullptr, nullptr, 1, 0);

    unsigned short* hin = h16a;
    unsigned short* hout = h16b;
    for (int l = 0; l < Ld; ++l) {
        hop_kernel<<<12500, 256, 0, stream>>>(hin, pb0, starts, src_s, w_s);
        hop_kernel<<<12500, 256, 0, stream>>>(pb0, pb1, starts, src_s, w_s);
        hop_kernel<<<12500, 256, 0, stream>>>(pb1, pb2, starts, src_s, w_s);
        int last = (l == Ld - 1);
        tag_gemm_mfma<<<gemm_grid, 256, 0, stream>>>(
            hin, pb0, pb1, pb2,
            WThi + (size_t)(1 + l * 4) * 16384, WTlo + (size_t)(1 + l * 4) * 16384,
            tagb + l * Hd, nullptr, last ? nullptr : hout,
            last ? oW : nullptr, last ? ob : nullptr, last ? y : nullptr,
            4, last ? 0 : 1);
        unsigned short* t = hin; hin = hout; hout = t;
    }
}